// Round 2
// baseline (4369.283 us; speedup 1.0000x reference)
//
#include <hip/hip_runtime.h>
#include <cmath>

#define Tn 512
#define Bn 32
#define Hn 1024
#define CH 64            // recurrence chunk (xg buffer = CH*4096*32*4 = 32 MB)

typedef short bf16x8 __attribute__((ext_vector_type(8)));
typedef float f32x4 __attribute__((ext_vector_type(4)));

__device__ __forceinline__ unsigned short f2bf_rne(float f) {
    unsigned u = __float_as_uint(f);
    unsigned r = (u + 0x7fffu + ((u >> 16) & 1u)) >> 16;
    return (unsigned short)r;
}
__device__ __forceinline__ float bf2f(unsigned short h) {
    return __uint_as_float((unsigned)h << 16);
}
__device__ __forceinline__ bf16x8 cvt8(float4 a, float4 b) {
    union { unsigned u[4]; bf16x8 v; } o;
    o.u[0] = (unsigned)f2bf_rne(a.x) | ((unsigned)f2bf_rne(a.y) << 16);
    o.u[1] = (unsigned)f2bf_rne(a.z) | ((unsigned)f2bf_rne(a.w) << 16);
    o.u[2] = (unsigned)f2bf_rne(b.x) | ((unsigned)f2bf_rne(b.y) << 16);
    o.u[3] = (unsigned)f2bf_rne(b.z) | ((unsigned)f2bf_rne(b.w) << 16);
    return o.v;
}
__device__ __forceinline__ bf16x8 as_bf8(uint4 u) {
    union { uint4 q; bf16x8 v; } o; o.q = u; return o.v;
}

// fast activations: v_exp + v_rcp approx (err ~1e-6 << bf16-h quantum 2^-9)
__device__ __forceinline__ float fsigf(float x) {
    return __builtin_amdgcn_rcpf(1.f + __expf(-x));
}
__device__ __forceinline__ float ftanhf(float x) {
    return 1.f - 2.f * __builtin_amdgcn_rcpf(1.f + __expf(2.f * x));
}

// ---- explicitly coherent (LLC point-of-coherence) access helpers ----------
__device__ __forceinline__ void gstore_u32_sc(unsigned* p, unsigned v) {
    asm volatile("global_store_dword %0, %1, off sc0 sc1\n\t"
                 "s_waitcnt vmcnt(0)"
                 :: "v"(p), "v"(v) : "memory");
}
__device__ __forceinline__ void gstore_u32_nd(unsigned* p, unsigned v) {
    asm volatile("global_store_dword %0, %1, off sc0 sc1"
                 :: "v"(p), "v"(v) : "memory");
}
__device__ __forceinline__ unsigned gload_u32_sc(const unsigned* p) {
    unsigned r;
    asm volatile("global_load_dword %0, %1, off sc0 sc1\n\t"
                 "s_waitcnt vmcnt(0)"
                 : "=&v"(r) : "v"(p) : "memory");
    return r;
}
__device__ __forceinline__ void gload_h_sc(const unsigned short* b0,
                                           const unsigned short* b1,
                                           uint4* o0, uint4* o1) {
    asm volatile(
        "global_load_dwordx4 %0, %8, off sc0 sc1\n\t"
        "global_load_dwordx4 %1, %8, off offset:64 sc0 sc1\n\t"
        "global_load_dwordx4 %2, %8, off offset:128 sc0 sc1\n\t"
        "global_load_dwordx4 %3, %8, off offset:192 sc0 sc1\n\t"
        "global_load_dwordx4 %4, %9, off sc0 sc1\n\t"
        "global_load_dwordx4 %5, %9, off offset:64 sc0 sc1\n\t"
        "global_load_dwordx4 %6, %9, off offset:128 sc0 sc1\n\t"
        "global_load_dwordx4 %7, %9, off offset:192 sc0 sc1\n\t"
        "s_waitcnt vmcnt(0)"
        : "=&v"(o0[0]), "=&v"(o0[1]), "=&v"(o0[2]), "=&v"(o0[3]),
          "=&v"(o1[0]), "=&v"(o1[1]), "=&v"(o1[2]), "=&v"(o1[3])
        : "v"(b0), "v"(b1)
        : "memory");
}

__global__ void lstm_flags_init(unsigned* flags) { flags[threadIdx.x] = 0u; }

// ---------------------------------------------------------------------------
// Kernel A: xg[tl][gc][b] = sum_k w_ih[gc][k] * x[b][t0+tl][k]  (hi/lo bf16
// split, fp32 accumulate -> numerically matches the old in-loop x-phase).
// Grid 256 = 32 gc-tiles(128) x 8 t-tiles(8). Waves split by t (so x is read
// once per block); w staged in LDS per K-tile of 128.
// ---------------------------------------------------------------------------
__global__ __launch_bounds__(512, 2) void lstm_xg_gemm(
    const float* __restrict__ x,       // [B,T,H]
    const float* __restrict__ w_ih,    // [4H,H]
    float* __restrict__ xg,            // ws: [CH][4096][32] fp32
    int t0)
{
    extern __shared__ char smem[];
    unsigned short* lds_a = (unsigned short*)smem;   // 256 rows x 136 bf16

    const int tid = threadIdx.x;
    const int gct = blockIdx.x & 31;   // gc-tile
    const int tt  = blockIdx.x >> 5;   // t-tile
    const int wv  = tid >> 6;
    const int ln  = tid & 63;
    const int l15 = ln & 15;
    const int qd  = ln >> 4;
    const int tl  = tt * 8 + wv;       // local t in chunk (wave-private)
    const int tg  = t0 + tl;

    f32x4 acc[8][2];
    #pragma unroll
    for (int gs = 0; gs < 8; ++gs)
        #pragma unroll
        for (int h2 = 0; h2 < 2; ++h2)
            acc[gs][h2] = (f32x4){0.f, 0.f, 0.f, 0.f};

    const float* xrow0 = x + (size_t)l15 * (Tn * Hn) + (size_t)tg * Hn + qd * 8;
    const float* xrow1 = xrow0 + (size_t)16 * (Tn * Hn);

    for (int kt = 0; kt < 8; ++kt) {
        // ---- stage w tile [128 gc][128 k] as hi/lo bf16 ----
        #pragma unroll
        for (int it = 0; it < 8; ++it) {
            int fi  = it * 512 + tid;
            int row = fi >> 5;         // 0..127
            int c   = fi & 31;         // float4 index in row
            float4 v = *(const float4*)(w_ih + (size_t)(gct * 128 + row) * Hn
                                        + kt * 128 + c * 4);
            unsigned short h0 = f2bf_rne(v.x), h1 = f2bf_rne(v.y);
            unsigned short h2 = f2bf_rne(v.z), h3 = f2bf_rne(v.w);
            unsigned short u0 = f2bf_rne(v.x - bf2f(h0)), u1 = f2bf_rne(v.y - bf2f(h1));
            unsigned short u2 = f2bf_rne(v.z - bf2f(h2)), u3 = f2bf_rne(v.w - bf2f(h3));
            uint2 ph, pl;
            ph.x = (unsigned)h0 | ((unsigned)h1 << 16);
            ph.y = (unsigned)h2 | ((unsigned)h3 << 16);
            pl.x = (unsigned)u0 | ((unsigned)u1 << 16);
            pl.y = (unsigned)u2 | ((unsigned)u3 << 16);
            *(uint2*)(lds_a + (size_t)row * 136 + c * 4) = ph;
            *(uint2*)(lds_a + (size_t)(row + 128) * 136 + c * 4) = pl;
        }
        __syncthreads();

        // ---- x fragments for this K-tile (wave-private t) ----
        float4 xv[4][4];
        #pragma unroll
        for (int kk = 0; kk < 4; ++kk) {
            xv[kk][0] = *(const float4*)(xrow0 + kt * 128 + kk * 32);
            xv[kk][1] = *(const float4*)(xrow0 + kt * 128 + kk * 32 + 4);
            xv[kk][2] = *(const float4*)(xrow1 + kt * 128 + kk * 32);
            xv[kk][3] = *(const float4*)(xrow1 + kt * 128 + kk * 32 + 4);
        }
        #pragma unroll
        for (int kk = 0; kk < 4; ++kk) {
            bf16x8 bf0 = cvt8(xv[kk][0], xv[kk][1]);
            bf16x8 bf1 = cvt8(xv[kk][2], xv[kk][3]);
            #pragma unroll
            for (int gs = 0; gs < 8; ++gs) {
                bf16x8 ahi = *(const bf16x8*)(lds_a + (size_t)(gs * 16 + l15) * 136
                                              + kk * 32 + qd * 8);
                bf16x8 alo = *(const bf16x8*)(lds_a + (size_t)(128 + gs * 16 + l15) * 136
                                              + kk * 32 + qd * 8);
                acc[gs][0] = __builtin_amdgcn_mfma_f32_16x16x32_bf16(ahi, bf0, acc[gs][0], 0, 0, 0);
                acc[gs][0] = __builtin_amdgcn_mfma_f32_16x16x32_bf16(alo, bf0, acc[gs][0], 0, 0, 0);
                acc[gs][1] = __builtin_amdgcn_mfma_f32_16x16x32_bf16(ahi, bf1, acc[gs][1], 0, 0, 0);
                acc[gs][1] = __builtin_amdgcn_mfma_f32_16x16x32_bf16(alo, bf1, acc[gs][1], 0, 0, 0);
            }
        }
        __syncthreads();
    }

    // ---- store: D row = qd*4+r (gc within 16-tile), col = l15 (+16 half) ----
    float* xgp = xg + (size_t)tl * (4096 * 32) + (size_t)(gct * 128) * 32 + l15;
    #pragma unroll
    for (int gs = 0; gs < 8; ++gs)
        #pragma unroll
        for (int h2 = 0; h2 < 2; ++h2)
            #pragma unroll
            for (int r = 0; r < 4; ++r)
                xgp[(size_t)(gs * 16 + qd * 4 + r) * 32 + h2 * 16] = acc[gs][h2][r];
}

// ---------------------------------------------------------------------------
// Kernel B: recurrence for one chunk. Per step: poll -> h (LLC) -> 16 h-MFMAs
// -> lds_r reduce (stride 18, conflict-free) -> finalize (+xg+bias) -> publish.
// x broadcast and x-MFMAs removed entirely (xg precomputed by kernel A).
// c-state persists in ws across chunk launches; flags carry global t.
// ---------------------------------------------------------------------------
__global__ __launch_bounds__(512, 2) void lstm_persist_mfma(
    const float* __restrict__ w_hh,    // [4H,H]
    const float* __restrict__ b_ih,    // [4H]
    const float* __restrict__ b_hh,    // [4H]
    const float* __restrict__ xg,      // ws: [CH][4096][32] fp32
    unsigned short* __restrict__ hbuf, // ws: 2 x [32][1024] bf16
    float* __restrict__ cbuf,          // ws: [32][1024] fp32
    unsigned* __restrict__ flags,      // ws: [256] u32
    float* __restrict__ out,           // [B,H] fp32
    int t0)
{
    extern __shared__ char smem[];
    unsigned short* lds_w = (unsigned short*)smem;            // 32 x 1032 bf16
    float* lds_r = (float*)(smem + 66048);                    // 16 x 288 f32
    unsigned* lds_cnt = (unsigned*)(smem + 66048 + 18432);    // 1 u32

    const int tid = threadIdx.x;
    const int bj  = blockIdx.x;
    const int wv  = tid >> 6;          // 0..7  k-slice
    const int ln  = tid & 63;
    const int l15 = ln & 15;
    const int qd  = ln >> 4;

    if (tid == 0) *lds_cnt = 0u;

    // ---- stage w_hh (hi+lo split bf16) into LDS, once per launch ----
    for (int i = 0; i < 8; ++i) {
        int slot = i * 512 + tid;
        int r    = slot >> 8;          // 0..15 (256 float4 per row)
        int f4   = slot & 255;
        int n    = (r >> 2) * Hn + bj * 4 + (r & 3);
        float4 v = ((const float4*)(w_hh + (size_t)n * Hn))[f4];
        unsigned short h0 = f2bf_rne(v.x), h1 = f2bf_rne(v.y);
        unsigned short h2 = f2bf_rne(v.z), h3 = f2bf_rne(v.w);
        unsigned short u0 = f2bf_rne(v.x - bf2f(h0)), u1 = f2bf_rne(v.y - bf2f(h1));
        unsigned short u2 = f2bf_rne(v.z - bf2f(h2)), u3 = f2bf_rne(v.w - bf2f(h3));
        uint2 ph, pl;
        ph.x = (unsigned)h0 | ((unsigned)h1 << 16);
        ph.y = (unsigned)h2 | ((unsigned)h3 << 16);
        pl.x = (unsigned)u0 | ((unsigned)u1 << 16);
        pl.y = (unsigned)u2 | ((unsigned)u3 << 16);
        *(uint2*)(lds_w + (size_t)r        * 1032 + f4 * 4) = ph;
        *(uint2*)(lds_w + (size_t)(r + 16) * 1032 + f4 * 4) = pl;
    }

    // finalize lanes: ln<16 of EVERY wave; element e = wv*16+ln
    float bias0 = 0.f, bias1 = 0.f, bias2 = 0.f, bias3 = 0.f, creg = 0.f;
    int fb = 0, fcl = 0;
    if (ln < 16) {
        const int e = (wv << 4) | ln;
        fb  = e >> 2;                  // batch 0..31
        fcl = e & 3;                   // col within block's 4
        int col = bj * 4 + fcl;
        bias0 = b_ih[col]          + b_hh[col];
        bias1 = b_ih[Hn + col]     + b_hh[Hn + col];
        bias2 = b_ih[2 * Hn + col] + b_hh[2 * Hn + col];
        bias3 = b_ih[3 * Hn + col] + b_hh[3 * Hn + col];
        if (t0 > 0) creg = cbuf[(size_t)fb * Hn + col];
    }
    __syncthreads();

    const unsigned short* whi_base = lds_w + (size_t)l15 * 1032 + qd * 8;
    const unsigned short* wlo_base = lds_w + (size_t)(l15 + 16) * 1032 + qd * 8;
    const size_t hoff0 = (size_t)l15        * Hn + wv * 128 + qd * 8;
    const size_t hoff1 = (size_t)(16 + l15) * Hn + wv * 128 + qd * 8;

    for (int t = t0; t < t0 + CH; ++t) {
        // ---- xg prefetch (written long before this launch; no race) ----
        float xg0 = 0.f, xg1 = 0.f, xg2 = 0.f, xg3 = 0.f;
        if (ln < 16) {
            const float* xp = xg + (size_t)(t - t0) * (4096 * 32)
                            + (size_t)(bj * 4 + fcl) * 32 + fb;
            xg0 = xp[0];
            xg1 = xp[1 * 1024 * 32];
            xg2 = xp[2 * 1024 * 32];
            xg3 = xp[3 * 1024 * 32];
        }

        f32x4 a0h = {0.f,0.f,0.f,0.f}, a0l = {0.f,0.f,0.f,0.f};
        f32x4 a1h = {0.f,0.f,0.f,0.f}, a1l = {0.f,0.f,0.f,0.f};

        // ---- per-wave producer-subset poll + h-phase ----
        if (t > 0) {
            {
                // lanes 0..31: producer blocks of this wave's k-slice;
                // lanes 32..63: own-block flag (orders lds_r overwrite).
                const int src = (ln < 32) ? (wv * 32 + ln) : bj;
                const unsigned* fp = flags + src;
                bool done = false;
                for (;;) {
                    if (!done) done = (gload_u32_sc(fp) >= (unsigned)t);
                    if (__all((int)done)) break;
                }
            }
            const unsigned short* hb = hbuf + (size_t)((t - 1) & 1) * (Bn * Hn);
            uint4 hf0[4], hf1[4];
            gload_h_sc(hb + hoff0, hb + hoff1, hf0, hf1);
            #pragma unroll
            for (int j = 0; j < 4; ++j) {
                const int koff = wv * 128 + j * 32;
                bf16x8 ahi = *(const bf16x8*)(whi_base + koff);
                bf16x8 alo = *(const bf16x8*)(wlo_base + koff);
                bf16x8 bf0 = as_bf8(hf0[j]);
                bf16x8 bf1 = as_bf8(hf1[j]);
                a0h = __builtin_amdgcn_mfma_f32_16x16x32_bf16(ahi, bf0, a0h, 0, 0, 0);
                a0l = __builtin_amdgcn_mfma_f32_16x16x32_bf16(alo, bf0, a0l, 0, 0, 0);
                a1h = __builtin_amdgcn_mfma_f32_16x16x32_bf16(ahi, bf1, a1h, 0, 0, 0);
                a1l = __builtin_amdgcn_mfma_f32_16x16x32_bf16(alo, bf1, a1l, 0, 0, 0);
            }
        }

        // ---- cross-wave k-reduction: write partials (stride 18 = 2-way max) --
        {
            f32x4 acc0 = a0h + a0l;
            f32x4 acc1 = a1h + a1l;
            float* pr0 = lds_r + (wv * 2 + 0) * 288 + l15;
            float* pr1 = lds_r + (wv * 2 + 1) * 288 + l15;
            #pragma unroll
            for (int r = 0; r < 4; ++r) {
                pr0[(qd * 4 + r) * 18] = acc0[r];   // D row = qd*4+r, col = l15
                pr1[(qd * 4 + r) * 18] = acc1[r];
            }
        }
        __syncthreads();   // the ONLY block barrier per step

        // ---- fused reduce + activations + h publish (16 lanes/wave) ----
        if (ln < 16) {
            const int bt = fb >> 4, c16 = fb & 15;
            float s0 = 0.f, s1 = 0.f, s2 = 0.f, s3 = 0.f;
            #pragma unroll
            for (int w8 = 0; w8 < 8; ++w8) {
                const float* base = lds_r + (w8 * 2 + bt) * 288 + c16;
                s0 += base[(0 * 4 + fcl) * 18];
                s1 += base[(1 * 4 + fcl) * 18];
                s2 += base[(2 * 4 + fcl) * 18];
                s3 += base[(3 * 4 + fcl) * 18];
            }
            float iv = fsigf(s0 + xg0 + bias0);
            float fv = fsigf(s1 + xg1 + bias1);
            float gv = ftanhf(s2 + xg2 + bias2);
            float ov = fsigf(s3 + xg3 + bias3);
            creg = fv * creg + iv * gv;
            float hn = ov * ftanhf(creg);
            unsigned short hv = f2bf_rne(hn);
            unsigned up = (unsigned)__shfl_xor((int)(unsigned)hv, 1, 64);
            if (!(ln & 1)) {          // fcl even: pack [fcl, fcl+1] into u32
                unsigned pack = (unsigned)hv | (up << 16);
                unsigned short* hw = hbuf + (size_t)(t & 1) * (Bn * Hn)
                                   + (size_t)fb * Hn + bj * 4 + fcl;
                gstore_u32_nd((unsigned*)hw, pack);
            }
            if (t == Tn - 1) out[(size_t)fb * Hn + bj * 4 + fcl] = hn;
            if (t == t0 + CH - 1) cbuf[(size_t)fb * Hn + bj * 4 + fcl] = creg;
        }
        // wave-wide drain of this wave's h stores (vmcnt is per-wave)
        asm volatile("s_waitcnt vmcnt(0)" ::: "memory");
        if (ln == 0) {
            unsigned lt = (unsigned)(t - t0);
            unsigned old = atomicAdd(lds_cnt, 1u);
            if (old == 8u * lt + 7u && (t + 1 < Tn))
                gstore_u32_sc(&flags[bj], (unsigned)(t + 1));
        }
    }
}

// ---------------------------------------------------------------------------
extern "C" void kernel_launch(void* const* d_in, const int* in_sizes, int n_in,
                              void* d_out, int out_size, void* d_ws, size_t ws_size,
                              hipStream_t stream) {
    const float* x    = (const float*)d_in[0];
    const float* w_ih = (const float*)d_in[1];
    const float* w_hh = (const float*)d_in[2];
    const float* b_ih = (const float*)d_in[3];
    const float* b_hh = (const float*)d_in[4];
    float* out = (float*)d_out;

    char* ws = (char*)d_ws;
    unsigned*       flags = (unsigned*)ws;                          // 1 KB
    unsigned short* hbuf  = (unsigned short*)(ws + 1024);           // 128 KB
    float*          cbuf  = (float*)(ws + 1024 + 131072);           // 128 KB
    float*          xg    = (float*)(ws + 1024 + 131072 + 131072);  // 32 MB
    (void)in_sizes; (void)n_in; (void)out_size; (void)ws_size;

    const size_t smem_a = 256 * 136 * 2;                  // 69632 B
    const size_t smem_b = 66048 + 18432 + 16;             // 84496 B

    lstm_flags_init<<<dim3(1), dim3(256), 0, stream>>>(flags);
    for (int c = 0; c < Tn / CH; ++c) {
        lstm_xg_gemm<<<dim3(256), dim3(512), smem_a, stream>>>(
            x, w_ih, xg, c * CH);
        lstm_persist_mfma<<<dim3(256), dim3(512), smem_b, stream>>>(
            w_hh, b_ih, b_hh, xg, hbuf, cbuf, flags, out, c * CH);
    }
}